// Round 3
// baseline (136.207 us; speedup 1.0000x reference)
//
#include <hip/hip_runtime.h>

typedef short bf16x8 __attribute__((ext_vector_type(8)));
typedef float f32x4  __attribute__((ext_vector_type(4)));
typedef short sh4    __attribute__((ext_vector_type(4)));
typedef float fl4    __attribute__((ext_vector_type(4)));
typedef unsigned u32x2 __attribute__((ext_vector_type(2)));
typedef unsigned u32x4 __attribute__((ext_vector_type(4)));

#define B_N  4
#define C_N  256
#define NH_N 8
#define DK_N 32
#define N_N  1024
#define KN_N 3072

#if defined(__has_builtin)
#if __has_builtin(__builtin_amdgcn_permlane32_swap) && __has_builtin(__builtin_amdgcn_permlane16_swap)
#define USE_PERMLANE 1
#endif
#endif
#ifndef USE_PERMLANE
#define USE_PERMLANE 0
#endif

__device__ __forceinline__ short f2bf(float f) {   // RNE
    union { float f; unsigned u; } v; v.f = f;
    unsigned r = v.u + 0x7fffu + ((v.u >> 16) & 1u);
    return (short)(r >> 16);
}
__device__ __forceinline__ unsigned fbits(float f) {
    union { float f; unsigned u; } v; v.f = f; return v.u;
}

// swizzled fp32 stage index for a 64c x 64n tile: conflict-free on both the
// n-vectorized write and the c-strided transposed read.
__device__ __forceinline__ int stg_idx(int c, int n) {
    return c * 64 + ((((n >> 2) ^ (c >> 2)) & 15) << 2) + (n & 3);
}

// ---------------- kernel 1: weights fp32 -> bf16 (Wq|Wk|Wv|Wo) -------------
__global__ __launch_bounds__(256) void wcvt_kernel(
    const float* __restrict__ Wq, const float* __restrict__ Wk,
    const float* __restrict__ Wv, const float* __restrict__ Wo,
    short* __restrict__ Wbf) {
    int e = (blockIdx.x * 256 + threadIdx.x) * 16;   // 64 blocks
    int m = e >> 16, off = e & 65535;
    const float* src = (m == 0) ? Wq : (m == 1) ? Wk : (m == 2) ? Wv : Wo;
    short* dst = Wbf + m * 65536 + off;
#pragma unroll
    for (int j = 0; j < 4; ++j) {
        fl4 v = *reinterpret_cast<const fl4*>(src + off + j * 4);
        sh4 o;
        o.x = f2bf(v.x); o.y = f2bf(v.y); o.z = f2bf(v.z); o.w = f2bf(v.w);
        *reinterpret_cast<sh4*>(dst + j * 4) = o;
    }
}

// ------- kernel 2: fused build + Q/K/V GEMM  grid(48, 4b) x 512 thr --------
// Block = (s, n0) tile, ALL 4 mt bands (256 output rows). The gamma-scaled
// transposed bf16 B-tile is built in LDS exactly once per tile chip-wide
// (no Xt round-trip). 8 waves: wave w owns weight rows [w*32, w*32+32).
// Epilogues K -> (Q) -> V sequentially alias the 48 KB LDS, all 16B stores.
__global__ __launch_bounds__(512, 2) void qkv_fused(
    const short* __restrict__ Wbf, const float* __restrict__ bq,
    const float* __restrict__ bk, const float* __restrict__ bv,
    const float* __restrict__ x0, const float* __restrict__ x1,
    const float* __restrict__ x2, const float* __restrict__ g0,
    const float* __restrict__ g1, const float* __restrict__ g2,
    short* __restrict__ Qs, short* __restrict__ Ks, short* __restrict__ Vt) {
    __shared__ __align__(16) char smem[49152];     // 48 KB
    float* stage = reinterpret_cast<float*>(smem);           // 16 KB
    short* Bt    = reinterpret_cast<short*>(smem + 16384);   // 32 KB [64n][256c] swz
    short* SMA   = reinterpret_cast<short*>(smem);           // epilogue alias

    int bx = blockIdx.x, b = blockIdx.y;
    int s = bx >> 4, n0 = (bx & 15) << 6;
    int t = threadIdx.x;
    int lane = t & 63, w = t >> 6;           // 8 waves
    int l16 = lane & 15, quad = lane >> 4;
    int mt = w >> 1, rg2 = w & 1;
    int r0 = mt * 64 + rg2 * 32;             // this wave's 32-row weight band
    bool hasQ = (s == 0);

    const float* xs = (s == 0) ? x0 : (s == 1) ? x1 : x2;
    float g = (s == 0) ? g0[0] : (s == 1) ? g1[0] : g2[0];
    const float* srcb = xs + (size_t)b * (C_N * N_N) + n0;

    // ---- build Bt[n][c] = bf16(g * x[c][n0+n]), byte-col ^= (n&7)<<4 ----
    for (int ch = 0; ch < 4; ++ch) {
        int c0 = ch << 6;
        {   // 1024 fl4 slots; 512 threads x 2. slot: cl=slot>>4, n4=(slot&15)*4
            int s1_ = t, s2_ = t + 512;
            int cl1 = s1_ >> 4, n41 = (s1_ & 15) << 2;
            int cl2 = s2_ >> 4, n42 = (s2_ & 15) << 2;
            fl4 v1 = *reinterpret_cast<const fl4*>(srcb + (size_t)(c0 + cl1) * N_N + n41);
            fl4 v2 = *reinterpret_cast<const fl4*>(srcb + (size_t)(c0 + cl2) * N_N + n42);
            v1.x *= g; v1.y *= g; v1.z *= g; v1.w *= g;
            v2.x *= g; v2.y *= g; v2.z *= g; v2.w *= g;
            *reinterpret_cast<fl4*>(&stage[stg_idx(cl1, n41)]) = v1;
            *reinterpret_cast<fl4*>(&stage[stg_idx(cl2, n42)]) = v2;
        }
        __syncthreads();
        {   // transpose+cvt: thread -> (n row, 8 consecutive c)
            int nl = t >> 3, cg = (t & 7) << 3;
            union { bf16x8 v8; short s16[8]; } pk;
#pragma unroll
            for (int i = 0; i < 8; ++i) pk.s16[i] = f2bf(stage[stg_idx(cg + i, nl)]);
            unsigned cb = ((unsigned)((c0 + cg) * 2)) ^ ((unsigned)((nl & 7) << 4));
            *reinterpret_cast<bf16x8*>(reinterpret_cast<char*>(Bt) + nl * 512 + cb) = pk.v8;
        }
        __syncthreads();
    }

    // ---- GEMM: acc[rg][nt] for K, V, (Q) ----
    f32x4 ak[2][4], av[2][4], aq[2][4];
#pragma unroll
    for (int rg = 0; rg < 2; ++rg)
#pragma unroll
        for (int nt = 0; nt < 4; ++nt) {
            ak[rg][nt] = f32x4{0.f, 0.f, 0.f, 0.f};
            av[rg][nt] = f32x4{0.f, 0.f, 0.f, 0.f};
            aq[rg][nt] = f32x4{0.f, 0.f, 0.f, 0.f};
        }
    const short* WqA = Wbf;
    const short* WkA = Wbf + 65536;
    const short* WvA = Wbf + 131072;
    unsigned xv = (unsigned)((l16 & 7) << 4);
    const char* btb = reinterpret_cast<const char*>(Bt);
#pragma unroll
    for (int kc = 0; kc < 256; kc += 32) {
        unsigned colb = ((unsigned)((kc + quad * 8) * 2)) ^ xv;
        bf16x8 bt0 = *reinterpret_cast<const bf16x8*>(btb + ((0  + l16) << 9) + colb);
        bf16x8 bt1 = *reinterpret_cast<const bf16x8*>(btb + ((16 + l16) << 9) + colb);
        bf16x8 bt2 = *reinterpret_cast<const bf16x8*>(btb + ((32 + l16) << 9) + colb);
        bf16x8 bt3 = *reinterpret_cast<const bf16x8*>(btb + ((48 + l16) << 9) + colb);
#pragma unroll
        for (int rg = 0; rg < 2; ++rg) {
            int ar = r0 + rg * 16 + l16;
            bf16x8 wk = *reinterpret_cast<const bf16x8*>(WkA + (size_t)ar * C_N + kc + quad * 8);
            ak[rg][0] = __builtin_amdgcn_mfma_f32_16x16x32_bf16(wk, bt0, ak[rg][0], 0, 0, 0);
            ak[rg][1] = __builtin_amdgcn_mfma_f32_16x16x32_bf16(wk, bt1, ak[rg][1], 0, 0, 0);
            ak[rg][2] = __builtin_amdgcn_mfma_f32_16x16x32_bf16(wk, bt2, ak[rg][2], 0, 0, 0);
            ak[rg][3] = __builtin_amdgcn_mfma_f32_16x16x32_bf16(wk, bt3, ak[rg][3], 0, 0, 0);
            bf16x8 wv = *reinterpret_cast<const bf16x8*>(WvA + (size_t)ar * C_N + kc + quad * 8);
            av[rg][0] = __builtin_amdgcn_mfma_f32_16x16x32_bf16(wv, bt0, av[rg][0], 0, 0, 0);
            av[rg][1] = __builtin_amdgcn_mfma_f32_16x16x32_bf16(wv, bt1, av[rg][1], 0, 0, 0);
            av[rg][2] = __builtin_amdgcn_mfma_f32_16x16x32_bf16(wv, bt2, av[rg][2], 0, 0, 0);
            av[rg][3] = __builtin_amdgcn_mfma_f32_16x16x32_bf16(wv, bt3, av[rg][3], 0, 0, 0);
            if (hasQ) {
                bf16x8 wq = *reinterpret_cast<const bf16x8*>(WqA + (size_t)ar * C_N + kc + quad * 8);
                aq[rg][0] = __builtin_amdgcn_mfma_f32_16x16x32_bf16(wq, bt0, aq[rg][0], 0, 0, 0);
                aq[rg][1] = __builtin_amdgcn_mfma_f32_16x16x32_bf16(wq, bt1, aq[rg][1], 0, 0, 0);
                aq[rg][2] = __builtin_amdgcn_mfma_f32_16x16x32_bf16(wq, bt2, aq[rg][2], 0, 0, 0);
                aq[rg][3] = __builtin_amdgcn_mfma_f32_16x16x32_bf16(wq, bt3, aq[rg][3], 0, 0, 0);
            }
        }
    }
    __syncthreads();     // all Bt reads done; epilogue aliases LDS

    // acc[rg][nt][i]: channel = r0 + rg*16 + quad*4 + i ; key-n = nt*16 + l16
    int hK = mt * 2 + rg2;                    // channel band >> 5

    // ---- K epilogue: SM_K[8 h][64 pos][40], then coalesced 16B stores ----
#pragma unroll
    for (int rg = 0; rg < 2; ++rg) {
        int crow = r0 + rg * 16 + quad * 4;
        float b0_ = bk[crow], b1_ = bk[crow + 1], b2_ = bk[crow + 2], b3_ = bk[crow + 3];
        short* Tp = SMA + hK * 2560 + rg * 16 + quad * 4;
#pragma unroll
        for (int nt = 0; nt < 4; ++nt) {
            int pos = (nt << 4) + l16;
            sh4 pk;
            pk.x = f2bf(ak[rg][nt][0] + b0_); pk.y = f2bf(ak[rg][nt][1] + b1_);
            pk.z = f2bf(ak[rg][nt][2] + b2_); pk.w = f2bf(ak[rg][nt][3] + b3_);
            *reinterpret_cast<sh4*>(Tp + pos * 40) = pk;
        }
    }
    __syncthreads();
#pragma unroll
    for (int j = 0; j < 4; ++j) {
        int u = j * 512 + t;
        int h = u >> 8, tt = u & 255;        // j=0: h0,1  j=1: h2,3 ...
        h += (j & 1) ? 0 : 0;                // (u>>8 already spans 0..7)
        bf16x8 vv = *reinterpret_cast<const bf16x8*>(SMA + h * 2560 + (tt >> 2) * 40 + (tt & 3) * 8);
        size_t base = ((size_t)(b * NH_N + h) * KN_N + s * N_N + n0) * DK_N;
        *reinterpret_cast<bf16x8*>(Ks + base + tt * 8) = vv;
    }
    __syncthreads();

    // ---- Q epilogue (s==0 blocks only) ----
    if (hasQ) {
        const float QSCALE = 0.17677669529663687f * 1.4426950408889634f;
#pragma unroll
        for (int rg = 0; rg < 2; ++rg) {
            int crow = r0 + rg * 16 + quad * 4;
            float b0_ = bq[crow], b1_ = bq[crow + 1], b2_ = bq[crow + 2], b3_ = bq[crow + 3];
            short* Tp = SMA + hK * 2560 + rg * 16 + quad * 4;
#pragma unroll
            for (int nt = 0; nt < 4; ++nt) {
                int pos = (nt << 4) + l16;
                sh4 pk;
                pk.x = f2bf((aq[rg][nt][0] + b0_) * QSCALE);
                pk.y = f2bf((aq[rg][nt][1] + b1_) * QSCALE);
                pk.z = f2bf((aq[rg][nt][2] + b2_) * QSCALE);
                pk.w = f2bf((aq[rg][nt][3] + b3_) * QSCALE);
                *reinterpret_cast<sh4*>(Tp + pos * 40) = pk;
            }
        }
        __syncthreads();
#pragma unroll
        for (int j = 0; j < 4; ++j) {
            int u = j * 512 + t;
            int h = u >> 8, tt = u & 255;
            bf16x8 vv = *reinterpret_cast<const bf16x8*>(SMA + h * 2560 + (tt >> 2) * 40 + (tt & 3) * 8);
            size_t base = ((size_t)(b * NH_N + h) * N_N + n0) * DK_N;
            *reinterpret_cast<bf16x8*>(Qs + base + tt * 8) = vv;
        }
        __syncthreads();
    }

    // ---- V epilogue: SMV[256 ch][72], keys contiguous, 16B stores ----
#pragma unroll
    for (int rg = 0; rg < 2; ++rg) {
        int crow = r0 + rg * 16 + quad * 4;
        float b0_ = bv[crow], b1_ = bv[crow + 1], b2_ = bv[crow + 2], b3_ = bv[crow + 3];
#pragma unroll
        for (int nt = 0; nt < 4; ++nt) {
            int pos = (nt << 4) + l16;
            SMA[(crow + 0) * 72 + pos] = f2bf(av[rg][nt][0] + b0_);
            SMA[(crow + 1) * 72 + pos] = f2bf(av[rg][nt][1] + b1_);
            SMA[(crow + 2) * 72 + pos] = f2bf(av[rg][nt][2] + b2_);
            SMA[(crow + 3) * 72 + pos] = f2bf(av[rg][nt][3] + b3_);
        }
    }
    __syncthreads();
#pragma unroll
    for (int j = 0; j < 4; ++j) {
        int u = j * 512 + t;
        int ch = u >> 3, seg = u & 7;
        bf16x8 vv = *reinterpret_cast<const bf16x8*>(SMA + ch * 72 + seg * 8);
        int h = ch >> 5, d = ch & 31;
        *reinterpret_cast<bf16x8*>(
            Vt + ((size_t)(b * NH_N + h) * DK_N + d) * KN_N + s * N_N + n0 + seg * 8) = vv;
    }
}

// -------- kernel 3: fused attention, 4 waves = 4 key-splits ----------------
struct Frags { bf16x8 k0, k1, k2, k3, v00, v01, v10, v11; };

__device__ __forceinline__ Frags ldfr(const short* Kp, const short* Vp0, int k0) {
    Frags f;
    f.k0  = *reinterpret_cast<const bf16x8*>(Kp + (k0 +  0) * DK_N);
    f.k1  = *reinterpret_cast<const bf16x8*>(Kp + (k0 + 16) * DK_N);
    f.k2  = *reinterpret_cast<const bf16x8*>(Kp + (k0 + 32) * DK_N);
    f.k3  = *reinterpret_cast<const bf16x8*>(Kp + (k0 + 48) * DK_N);
    f.v00 = *reinterpret_cast<const bf16x8*>(Vp0 + k0);
    f.v01 = *reinterpret_cast<const bf16x8*>(Vp0 + 16 * KN_N + k0);
    f.v10 = *reinterpret_cast<const bf16x8*>(Vp0 + k0 + 32);
    f.v11 = *reinterpret_cast<const bf16x8*>(Vp0 + 16 * KN_N + k0 + 32);
    return f;
}

#define EXPPACK(sv, Ra, Rb, LACC) {                             \
    float p0 = __builtin_amdgcn_exp2f(sv[0]);                   \
    float p1 = __builtin_amdgcn_exp2f(sv[1]);                   \
    float p2 = __builtin_amdgcn_exp2f(sv[2]);                   \
    float p3 = __builtin_amdgcn_exp2f(sv[3]);                   \
    LACC += (p0 + p1) + (p2 + p3);                              \
    Ra = __builtin_amdgcn_perm(fbits(p1), fbits(p0), 0x07060302u); \
    Rb = __builtin_amdgcn_perm(fbits(p3), fbits(p2), 0x07060302u); \
}

#if USE_PERMLANE
#define PVSTEP(RA0, RA1, RB0, RB1, VF0, VF1, O0, O1) {                 \
    unsigned x0 = RA0, y0 = RB0, x1 = RA1, y1 = RB1;                   \
    u32x2 r_;                                                          \
    r_ = __builtin_amdgcn_permlane32_swap(x0, y0, false, false); x0 = r_.x; y0 = r_.y; \
    r_ = __builtin_amdgcn_permlane16_swap(x0, y0, false, false); x0 = r_.x; y0 = r_.y; \
    r_ = __builtin_amdgcn_permlane32_swap(x1, y1, false, false); x1 = r_.x; y1 = r_.y; \
    r_ = __builtin_amdgcn_permlane16_swap(x1, y1, false, false); x1 = r_.x; y1 = r_.y; \
    union { u32x4 u; bf16x8 b; } pf_; pf_.u = u32x4{x0, x1, y0, y1};   \
    __builtin_amdgcn_s_setprio(1);                                     \
    O0 = __builtin_amdgcn_mfma_f32_16x16x32_bf16(VF0, pf_.b, O0, 0, 0, 0); \
    O1 = __builtin_amdgcn_mfma_f32_16x16x32_bf16(VF1, pf_.b, O1, 0, 0, 0); \
    __builtin_amdgcn_s_setprio(0);                                     \
}
#else
#define PVSTEP(RA0, RA1, RB0, RB1, VF0, VF1, O0, O1) {                 \
    union { u32x2 u; sh4 s; } wa_, wb_;                                \
    wa_.u = u32x2{RA0, RA1}; wb_.u = u32x2{RB0, RB1};                  \
    *reinterpret_cast<sh4*>(&PT[w][l16][quad * 4])      = wa_.s;       \
    *reinterpret_cast<sh4*>(&PT[w][l16][16 + quad * 4]) = wb_.s;       \
    bf16x8 pf_ = *reinterpret_cast<bf16x8*>(&PT[w][l16][quad * 8]);    \
    O0 = __builtin_amdgcn_mfma_f32_16x16x32_bf16(VF0, pf_, O0, 0, 0, 0); \
    O1 = __builtin_amdgcn_mfma_f32_16x16x32_bf16(VF1, pf_, O1, 0, 0, 0); \
}
#endif

#define PROCJ(f, QF, LACC, O0, O1) {                                     \
    __builtin_amdgcn_s_setprio(1);                                       \
    f32x4 s0 = __builtin_amdgcn_mfma_f32_16x16x32_bf16(f.k0, QF, zero, 0, 0, 0); \
    f32x4 s1 = __builtin_amdgcn_mfma_f32_16x16x32_bf16(f.k1, QF, zero, 0, 0, 0); \
    f32x4 s2 = __builtin_amdgcn_mfma_f32_16x16x32_bf16(f.k2, QF, zero, 0, 0, 0); \
    f32x4 s3 = __builtin_amdgcn_mfma_f32_16x16x32_bf16(f.k3, QF, zero, 0, 0, 0); \
    __builtin_amdgcn_s_setprio(0);                                       \
    unsigned R00, R01, R10, R11, R20, R21, R30, R31;                     \
    EXPPACK(s0, R00, R01, LACC); EXPPACK(s1, R10, R11, LACC);            \
    EXPPACK(s2, R20, R21, LACC); EXPPACK(s3, R30, R31, LACC);            \
    PVSTEP(R00, R01, R10, R11, f.v00, f.v01, O0, O1);                    \
    PVSTEP(R20, R21, R30, R31, f.v10, f.v11, O0, O1);                    \
}

#define PROCALL(f) {                                                     \
    PROCJ(f, qf0, la0, o00, o01);                                        \
    PROCJ(f, qf1, la1, o10, o11);                                        \
    PROCJ(f, qf2, la2, o20, o21);                                        \
    PROCJ(f, qf3, la3, o30, o31);                                        \
}

__global__ __launch_bounds__(256, 2) void attn_kernel(
    const short* __restrict__ Qs, const short* __restrict__ Ks,
    const short* __restrict__ Vt, short* __restrict__ Ot) {
    __shared__ float OL[4][64][36];   // [split][q][d] partial O
    __shared__ float Ll[4][64];       // [split][q] partial rowsum
#if !USE_PERMLANE
    __shared__ short PT[4][16][36];
#endif

    int bh = blockIdx.x;
    int q0 = blockIdx.y * 64;
    int t = threadIdx.x, lane = t & 63, w = t >> 6;   // w = key-split 0..3
    int l16 = lane & 15, quad = lane >> 4;

    const short* Qbase = Qs + ((size_t)bh * N_N + q0 + l16) * DK_N + quad * 8;
    bf16x8 qf0 = *reinterpret_cast<const bf16x8*>(Qbase + 0 * 16 * DK_N);
    bf16x8 qf1 = *reinterpret_cast<const bf16x8*>(Qbase + 1 * 16 * DK_N);
    bf16x8 qf2 = *reinterpret_cast<const bf16x8*>(Qbase + 2 * 16 * DK_N);
    bf16x8 qf3 = *reinterpret_cast<const bf16x8*>(Qbase + 3 * 16 * DK_N);
    const short* Kp  = Ks + ((size_t)bh * KN_N + l16) * DK_N + quad * 8;
    const short* Vp0 = Vt + ((size_t)bh * DK_N + l16) * KN_N + quad * 8;

    const f32x4 zero = {0.f, 0.f, 0.f, 0.f};
    f32x4 o00 = zero, o01 = zero, o10 = zero, o11 = zero;
    f32x4 o20 = zero, o21 = zero, o30 = zero, o31 = zero;
    float la0 = 0.f, la1 = 0.f, la2 = 0.f, la3 = 0.f;
    int kbase = w * 768;              // this wave's 768-key slice, 12 tiles

    Frags cur = ldfr(Kp, Vp0, kbase);
#pragma unroll 2
    for (int i = 0; i < 11; ++i) {
        Frags nxt = ldfr(Kp, Vp0, kbase + (i + 1) * 64);   // prefetch next tile
        PROCALL(cur);
        cur = nxt;
    }
    PROCALL(cur);

    la0 += __shfl_xor(la0, 16); la0 += __shfl_xor(la0, 32);
    la1 += __shfl_xor(la1, 16); la1 += __shfl_xor(la1, 32);
    la2 += __shfl_xor(la2, 16); la2 += __shfl_xor(la2, 32);
    la3 += __shfl_xor(la3, 16); la3 += __shfl_xor(la3, 32);

    *reinterpret_cast<fl4*>(&OL[w][ 0 + l16][quad * 4])      = o00;
    *reinterpret_cast<fl4*>(&OL[w][ 0 + l16][16 + quad * 4]) = o01;
    *reinterpret_cast<fl4*>(&OL[w][16 + l16][quad * 4])      = o10;
    *reinterpret_cast<fl4*>(&OL[w][16 + l16][16 + quad * 4]) = o11;
    *reinterpret_cast<fl4*>(&OL[w][32 + l16][quad * 4])      = o20;
    *reinterpret_cast<fl4*>(&OL[w][32 + l16][16 + quad * 4]) = o21;
    *reinterpret_cast<fl4*>(&OL[w][48 + l16][quad * 4])      = o30;
    *reinterpret_cast<fl4*>(&OL[w][48 + l16][16 + quad * 4]) = o31;
    if (quad == 0) {
        Ll[w][ 0 + l16] = la0;
        Ll[w][16 + l16] = la1;
        Ll[w][32 + l16] = la2;
        Ll[w][48 + l16] = la3;
    }
    __syncthreads();

    int q = t >> 2, d0 = (t & 3) * 8;
    float rl = 1.0f / (Ll[0][q] + Ll[1][q] + Ll[2][q] + Ll[3][q]);
    fl4 a0 = *reinterpret_cast<fl4*>(&OL[0][q][d0]);
    fl4 a1 = *reinterpret_cast<fl4*>(&OL[0][q][d0 + 4]);
#pragma unroll
    for (int s = 1; s < 4; ++s) {
        fl4 b0 = *reinterpret_cast<fl4*>(&OL[s][q][d0]);
        fl4 b1 = *reinterpret_cast<fl4*>(&OL[s][q][d0 + 4]);
        a0.x += b0.x; a0.y += b0.y; a0.z += b0.z; a0.w += b0.w;
        a1.x += b1.x; a1.y += b1.y; a1.z += b1.z; a1.w += b1.w;
    }
    union { sh4 s[2]; bf16x8 v; } pk;
    pk.s[0].x = f2bf(a0.x * rl); pk.s[0].y = f2bf(a0.y * rl);
    pk.s[0].z = f2bf(a0.z * rl); pk.s[0].w = f2bf(a0.w * rl);
    pk.s[1].x = f2bf(a1.x * rl); pk.s[1].y = f2bf(a1.y * rl);
    pk.s[1].z = f2bf(a1.z * rl); pk.s[1].w = f2bf(a1.w * rl);
    int b = bh >> 3, h = bh & 7;
    *reinterpret_cast<bf16x8*>(
        Ot + ((size_t)b * N_N + q0 + q) * C_N + h * DK_N + d0) = pk.v;
}

// ---------------- kernel 4: output projection  grid(32 ct, 4 mt, 4 b) ------
__global__ __launch_bounds__(256) void oproj_kernel(
    const short* __restrict__ Wo_bf, const float* __restrict__ bo,
    const short* __restrict__ Ot, float* __restrict__ out) {
    int b = blockIdx.z, mt = blockIdx.y, ct = blockIdx.x;
    int lane = threadIdx.x & 63, w = threadIdx.x >> 6;
    int l16 = lane & 15, quad = lane >> 4;
    int m0 = mt * 64, n0 = ct * 32;
    const short* Bsrc = Ot + ((size_t)b * N_N + n0) * C_N;
    int arow = m0 + w * 16 + l16;

    f32x4 acc[2];
    acc[0] = f32x4{0.f, 0.f, 0.f, 0.f};
    acc[1] = f32x4{0.f, 0.f, 0.f, 0.f};

#pragma unroll
    for (int kc = 0; kc < 256; kc += 32) {
        bf16x8 a = *reinterpret_cast<const bf16x8*>(Wo_bf + arow * C_N + kc + quad * 8);
#pragma unroll
        for (int nt = 0; nt < 2; ++nt) {
            bf16x8 bb = *reinterpret_cast<const bf16x8*>(Bsrc + (nt * 16 + l16) * C_N + kc + quad * 8);
            acc[nt] = __builtin_amdgcn_mfma_f32_16x16x32_bf16(a, bb, acc[nt], 0, 0, 0);
        }
    }

#pragma unroll
    for (int r = 0; r < 4; ++r) {
        int row = m0 + w * 16 + quad * 4 + r;
        float bias = bo[row];
#pragma unroll
        for (int nt = 0; nt < 2; ++nt) {
            out[((size_t)b * C_N + row) * N_N + n0 + nt * 16 + l16] = acc[nt][r] + bias;
        }
    }
}

// ---------------------------------------------------------------------------
extern "C" void kernel_launch(void* const* d_in, const int* in_sizes, int n_in,
                              void* d_out, int out_size, void* d_ws, size_t ws_size,
                              hipStream_t stream) {
    const float* x0 = (const float*)d_in[0];
    const float* x1 = (const float*)d_in[1];
    const float* x2 = (const float*)d_in[2];
    const float* g0 = (const float*)d_in[3];
    const float* g1 = (const float*)d_in[4];
    const float* g2 = (const float*)d_in[5];
    const float* Wq = (const float*)d_in[6];
    const float* bq = (const float*)d_in[7];
    const float* Wk = (const float*)d_in[8];
    const float* bk = (const float*)d_in[9];
    const float* Wv = (const float*)d_in[10];
    const float* bv = (const float*)d_in[11];
    const float* Wo = (const float*)d_in[12];
    const float* bo = (const float*)d_in[13];
    float* out = (float*)d_out;

    char* wsb = (char*)d_ws;
    short* Wbf = (short*)(wsb + 0);            //  512 KB (Wq|Wk|Wv|Wo bf16)
    short* Qs  = (short*)(wsb + 6815744);      //  2 MB: [4][8][1024][32]
    short* Ks  = (short*)(wsb + 8912896);      //  6 MB: [4][8][3072][32]
    short* Vt  = (short*)(wsb + 15204352);     //  6 MB: [4][8][32][3072]
    short* Ot  = (short*)(wsb + 21495808);     //  2 MB: [4][1024][256]

    wcvt_kernel<<<64, 256, 0, stream>>>(Wq, Wk, Wv, Wo, Wbf);
    qkv_fused<<<dim3(48, 4), 512, 0, stream>>>(Wbf, bq, bk, bv,
                                               x0, x1, x2, g0, g1, g2,
                                               Qs, Ks, Vt);
    attn_kernel<<<dim3(32, 16), 256, 0, stream>>>(Qs, Ks, Vt, Ot);
    oproj_kernel<<<dim3(32, 4, 4), 256, 0, stream>>>(Wbf + 3 * 65536, bo, Ot, out);
}

// Round 4
// 132.506 us; speedup vs baseline: 1.0279x; 1.0279x over previous
//
#include <hip/hip_runtime.h>

typedef short bf16x8 __attribute__((ext_vector_type(8)));
typedef float f32x4  __attribute__((ext_vector_type(4)));
typedef short sh4    __attribute__((ext_vector_type(4)));
typedef float fl4    __attribute__((ext_vector_type(4)));
typedef unsigned u32x2 __attribute__((ext_vector_type(2)));
typedef unsigned u32x4 __attribute__((ext_vector_type(4)));

#define B_N  4
#define C_N  256
#define NH_N 8
#define DK_N 32
#define N_N  1024
#define KN_N 3072

#if defined(__has_builtin)
#if __has_builtin(__builtin_amdgcn_permlane32_swap) && __has_builtin(__builtin_amdgcn_permlane16_swap)
#define USE_PERMLANE 1
#endif
#endif
#ifndef USE_PERMLANE
#define USE_PERMLANE 0
#endif

__device__ __forceinline__ short f2bf(float f) {   // RNE
    union { float f; unsigned u; } v; v.f = f;
    unsigned r = v.u + 0x7fffu + ((v.u >> 16) & 1u);
    return (short)(r >> 16);
}
__device__ __forceinline__ unsigned fbits(float f) {
    union { float f; unsigned u; } v; v.f = f; return v.u;
}

// swizzled fp32 stage index for a 64c x 64n tile: conflict-free on both the
// n-vectorized write and the c-strided transposed read.
__device__ __forceinline__ int stg_idx(int c, int n) {
    return c * 64 + ((((n >> 2) ^ (c >> 2)) & 15) << 2) + (n & 3);
}

// ---------------- kernel 1: prep ------------------------------------------
// blocks 0..191 : Xt[b*3+s][n][c] = bf16(gamma_s * x_s[b][c][n]), stored with
//                 the byte-XOR swizzle  byte ^= (n&7)<<4  within each 512B row
//                 so the GEMM can stage it with LINEAR global_load_lds and
//                 read conflict-free with the same XOR.
// blocks 192..255: Wq|Wk|Wv|Wo fp32 -> bf16 (concat, unswizzled).
__global__ __launch_bounds__(256) void prep_kernel(
    const float* __restrict__ x0, const float* __restrict__ x1,
    const float* __restrict__ x2, const float* __restrict__ g0,
    const float* __restrict__ g1, const float* __restrict__ g2,
    const float* __restrict__ Wq, const float* __restrict__ Wk,
    const float* __restrict__ Wv, const float* __restrict__ Wo,
    short* __restrict__ Xt, short* __restrict__ Wbf) {
    __shared__ float stage[4096];      // 16 KB, one 64c x 64n chunk
    int bx = blockIdx.x, t = threadIdx.x;
    if (bx >= 192) {                   // ---- weight convert ----
        int e = (bx - 192) * 4096 + t * 16;
        int m = e >> 16, off = e & 65535;
        const float* src = (m == 0) ? Wq : (m == 1) ? Wk : (m == 2) ? Wv : Wo;
        short* dst = Wbf + m * 65536 + off;
#pragma unroll
        for (int j = 0; j < 4; ++j) {
            fl4 v = *reinterpret_cast<const fl4*>(src + off + j * 4);
            sh4 o;
            o.x = f2bf(v.x); o.y = f2bf(v.y); o.z = f2bf(v.z); o.w = f2bf(v.w);
            *reinterpret_cast<sh4*>(dst + j * 4) = o;
        }
        return;
    }
    int bs = bx >> 4;                  // b*3 + s
    int n0 = (bx & 15) << 6;
    int b = bs / 3, s = bs - b * 3;
    const float* xs = (s == 0) ? x0 : (s == 1) ? x1 : x2;
    float g = (s == 0) ? g0[0] : (s == 1) ? g1[0] : g2[0];
    const float* srcb = xs + (size_t)b * C_N * N_N;
    int n4 = (t & 15) << 2;
    for (int ch = 0; ch < 4; ++ch) {
        int c0 = ch << 6;
#pragma unroll
        for (int r = 0; r < 4; ++r) {
            int cl = (t >> 4) + (r << 4);
            fl4 v = *reinterpret_cast<const fl4*>(srcb + (size_t)(c0 + cl) * N_N + n0 + n4);
            v.x *= g; v.y *= g; v.z *= g; v.w *= g;
            *reinterpret_cast<fl4*>(&stage[stg_idx(cl, n4)]) = v;
        }
        __syncthreads();
#pragma unroll
        for (int j = 0; j < 2; ++j) {
            int u = t + (j << 8);
            int nl = u >> 3, cg = (u & 7) << 3;     // 8 lanes cover 128B of one row
            union { bf16x8 v8; short s16[8]; } pk;
#pragma unroll
            for (int i = 0; i < 8; ++i) pk.s16[i] = f2bf(stage[stg_idx(cg + i, nl)]);
            size_t rowsh = ((size_t)bs * N_N + n0 + nl) * C_N;
            unsigned cb = ((unsigned)((c0 + cg) * 2)) ^ ((unsigned)((nl & 7) << 4));
            *reinterpret_cast<bf16x8*>((char*)Xt + rowsh * 2 + cb) = pk.v8;
        }
        __syncthreads();
    }
}

// ------- kernel 2: merged Q+K+V GEMM  grid(48 ct, 4 mt, 4 b) ---------------
// ct = s*16 + n0/64. One 32KB swizzled B-tile staged via global_load_lds is
// shared by the K GEMM, the V GEMM (both weights-as-A) and, for s==0 blocks,
// the Q GEMM. Epilogues repack via (Bt-aliased) LDS for coalesced 16B stores.
__global__ __launch_bounds__(256) void qkv_kernel(
    const short* __restrict__ Wbf, const float* __restrict__ bq,
    const float* __restrict__ bk, const float* __restrict__ bv,
    const short* __restrict__ Xt,
    short* __restrict__ Qs, short* __restrict__ Ks, short* __restrict__ Vt) {
    __shared__ short Bt[16384];        // 32 KB; epilogue aliases disjoint parts
    int b = blockIdx.z, mt = blockIdx.y, ct = blockIdx.x;
    int s = ct >> 4, n0 = (ct & 15) << 6;
    int t = threadIdx.x, lane = t & 63, w = t >> 6;
    int l16 = lane & 15, quad = lane >> 4;
    int m0 = mt << 6;
    bool hasQ = (s == 0);

    // ---- stage: linear 32KB copy (Xt already byte-swizzled) ----
    const char* gsrc = (const char*)(Xt + (((size_t)(b * 3 + s)) * N_N + n0) * C_N);
    char* ldst = (char*)Bt;
#pragma unroll
    for (int i = 0; i < 8; ++i) {
        int off = ((w << 3) + i) << 10;
        __builtin_amdgcn_global_load_lds(
            (const __attribute__((address_space(1))) void*)(gsrc + off + lane * 16),
            (__attribute__((address_space(3))) void*)(ldst + off), 16, 0, 0);
    }
    __syncthreads();

    f32x4 aq[4], ak[4], av[4];
#pragma unroll
    for (int i = 0; i < 4; ++i) {
        aq[i] = f32x4{0.f, 0.f, 0.f, 0.f};
        ak[i] = f32x4{0.f, 0.f, 0.f, 0.f};
        av[i] = f32x4{0.f, 0.f, 0.f, 0.f};
    }
    const short* WqA = Wbf;
    const short* WkA = Wbf + 65536;
    const short* WvA = Wbf + 131072;
    int arow = m0 + (w << 4) + l16;
    unsigned xv = (unsigned)((l16 & 7) << 4);   // read-side XOR (row&7 == l16&7)
    const char* btb = (const char*)Bt;
#pragma unroll
    for (int kc = 0; kc < 256; kc += 32) {
        unsigned colb = ((unsigned)((kc + quad * 8) * 2)) ^ xv;
        bf16x8 bt0 = *reinterpret_cast<const bf16x8*>(btb + ((0  + l16) << 9) + colb);
        bf16x8 bt1 = *reinterpret_cast<const bf16x8*>(btb + ((16 + l16) << 9) + colb);
        bf16x8 bt2 = *reinterpret_cast<const bf16x8*>(btb + ((32 + l16) << 9) + colb);
        bf16x8 bt3 = *reinterpret_cast<const bf16x8*>(btb + ((48 + l16) << 9) + colb);
        bf16x8 wk = *reinterpret_cast<const bf16x8*>(WkA + (size_t)arow * C_N + kc + quad * 8);
        ak[0] = __builtin_amdgcn_mfma_f32_16x16x32_bf16(wk, bt0, ak[0], 0, 0, 0);
        ak[1] = __builtin_amdgcn_mfma_f32_16x16x32_bf16(wk, bt1, ak[1], 0, 0, 0);
        ak[2] = __builtin_amdgcn_mfma_f32_16x16x32_bf16(wk, bt2, ak[2], 0, 0, 0);
        ak[3] = __builtin_amdgcn_mfma_f32_16x16x32_bf16(wk, bt3, ak[3], 0, 0, 0);
        bf16x8 wv = *reinterpret_cast<const bf16x8*>(WvA + (size_t)arow * C_N + kc + quad * 8);
        av[0] = __builtin_amdgcn_mfma_f32_16x16x32_bf16(wv, bt0, av[0], 0, 0, 0);
        av[1] = __builtin_amdgcn_mfma_f32_16x16x32_bf16(wv, bt1, av[1], 0, 0, 0);
        av[2] = __builtin_amdgcn_mfma_f32_16x16x32_bf16(wv, bt2, av[2], 0, 0, 0);
        av[3] = __builtin_amdgcn_mfma_f32_16x16x32_bf16(wv, bt3, av[3], 0, 0, 0);
        if (hasQ) {
            bf16x8 wq = *reinterpret_cast<const bf16x8*>(WqA + (size_t)arow * C_N + kc + quad * 8);
            aq[0] = __builtin_amdgcn_mfma_f32_16x16x32_bf16(wq, bt0, aq[0], 0, 0, 0);
            aq[1] = __builtin_amdgcn_mfma_f32_16x16x32_bf16(wq, bt1, aq[1], 0, 0, 0);
            aq[2] = __builtin_amdgcn_mfma_f32_16x16x32_bf16(wq, bt2, aq[2], 0, 0, 0);
            aq[3] = __builtin_amdgcn_mfma_f32_16x16x32_bf16(wq, bt3, aq[3], 0, 0, 0);
        }
    }
    __syncthreads();   // all Bt reads done; epilogue aliases it

    short* SMq = Bt;              // 5120 shorts: 2 x [64 pos][40]
    short* SMk = Bt + 5120;       // 5120 shorts
    short* SMv = Bt + 10240;      // 4608 shorts: [64 ch][72]
    int row0 = m0 + (w << 4) + (quad << 2);
    int dk0 = ((w & 1) << 4) + (quad << 2);
    {
        float kb0 = bk[row0], kb1 = bk[row0 + 1], kb2 = bk[row0 + 2], kb3 = bk[row0 + 3];
        short* Tp = SMk + (w >> 1) * 2560 + dk0;
#pragma unroll
        for (int nt = 0; nt < 4; ++nt) {
            int pos = (nt << 4) + l16;
            sh4 pk;
            pk.x = f2bf(ak[nt][0] + kb0); pk.y = f2bf(ak[nt][1] + kb1);
            pk.z = f2bf(ak[nt][2] + kb2); pk.w = f2bf(ak[nt][3] + kb3);
            *reinterpret_cast<sh4*>(Tp + pos * 40) = pk;
        }
    }
    if (hasQ) {
        const float QSCALE = 0.17677669529663687f * 1.4426950408889634f;
        float qb0 = bq[row0], qb1 = bq[row0 + 1], qb2 = bq[row0 + 2], qb3 = bq[row0 + 3];
        short* Tp = SMq + (w >> 1) * 2560 + dk0;
#pragma unroll
        for (int nt = 0; nt < 4; ++nt) {
            int pos = (nt << 4) + l16;
            sh4 pk;
            pk.x = f2bf((aq[nt][0] + qb0) * QSCALE); pk.y = f2bf((aq[nt][1] + qb1) * QSCALE);
            pk.z = f2bf((aq[nt][2] + qb2) * QSCALE); pk.w = f2bf((aq[nt][3] + qb3) * QSCALE);
            *reinterpret_cast<sh4*>(Tp + pos * 40) = pk;
        }
    }
    {
        int crow = (w << 4) + (quad << 2);      // local output channel
        float vb0 = bv[m0 + crow], vb1 = bv[m0 + crow + 1];
        float vb2 = bv[m0 + crow + 2], vb3 = bv[m0 + crow + 3];
#pragma unroll
        for (int nt = 0; nt < 4; ++nt) {
            int pos = (nt << 4) + l16;
            SMv[(crow + 0) * 72 + pos] = f2bf(av[nt][0] + vb0);
            SMv[(crow + 1) * 72 + pos] = f2bf(av[nt][1] + vb1);
            SMv[(crow + 2) * 72 + pos] = f2bf(av[nt][2] + vb2);
            SMv[(crow + 3) * 72 + pos] = f2bf(av[nt][3] + vb3);
        }
    }
    __syncthreads();

    {
        int pos_l = t >> 2, seg = t & 3;
#pragma unroll
        for (int hl = 0; hl < 2; ++hl) {
            int h = 2 * mt + hl;
            bf16x8 kv = *reinterpret_cast<const bf16x8*>(SMk + hl * 2560 + pos_l * 40 + seg * 8);
            *reinterpret_cast<bf16x8*>(
                Ks + ((size_t)(b * NH_N + h) * KN_N + s * N_N + n0) * DK_N + t * 8) = kv;
            if (hasQ) {
                bf16x8 qv = *reinterpret_cast<const bf16x8*>(SMq + hl * 2560 + pos_l * 40 + seg * 8);
                *reinterpret_cast<bf16x8*>(
                    Qs + ((size_t)(b * NH_N + h) * N_N + n0) * DK_N + t * 8) = qv;
            }
        }
#pragma unroll
        for (int i = 0; i < 2; ++i) {
            int chn = t + (i << 8);
            int row = chn >> 3, seg2 = chn & 7;
            bf16x8 vv = *reinterpret_cast<const bf16x8*>(SMv + row * 72 + seg2 * 8);
            int co = m0 + row;
            int h = co >> 5, d = co & 31;
            *reinterpret_cast<bf16x8*>(
                Vt + ((size_t)(b * NH_N + h) * DK_N + d) * KN_N + s * N_N + n0 + seg2 * 8) = vv;
        }
    }
}

// -------- kernel 3: fused attention, 4 waves = 4 key-splits ----------------
struct Frags { bf16x8 k0, k1, k2, k3, v00, v01, v10, v11; };

__device__ __forceinline__ Frags ldfr(const short* Kp, const short* Vp0, int k0) {
    Frags f;
    f.k0  = *reinterpret_cast<const bf16x8*>(Kp + (k0 +  0) * DK_N);
    f.k1  = *reinterpret_cast<const bf16x8*>(Kp + (k0 + 16) * DK_N);
    f.k2  = *reinterpret_cast<const bf16x8*>(Kp + (k0 + 32) * DK_N);
    f.k3  = *reinterpret_cast<const bf16x8*>(Kp + (k0 + 48) * DK_N);
    f.v00 = *reinterpret_cast<const bf16x8*>(Vp0 + k0);
    f.v01 = *reinterpret_cast<const bf16x8*>(Vp0 + 16 * KN_N + k0);
    f.v10 = *reinterpret_cast<const bf16x8*>(Vp0 + k0 + 32);
    f.v11 = *reinterpret_cast<const bf16x8*>(Vp0 + 16 * KN_N + k0 + 32);
    return f;
}

#define EXPPACK(sv, Ra, Rb, LACC) {                             \
    float p0 = __builtin_amdgcn_exp2f(sv[0]);                   \
    float p1 = __builtin_amdgcn_exp2f(sv[1]);                   \
    float p2 = __builtin_amdgcn_exp2f(sv[2]);                   \
    float p3 = __builtin_amdgcn_exp2f(sv[3]);                   \
    LACC += (p0 + p1) + (p2 + p3);                              \
    Ra = __builtin_amdgcn_perm(fbits(p1), fbits(p0), 0x07060302u); \
    Rb = __builtin_amdgcn_perm(fbits(p3), fbits(p2), 0x07060302u); \
}

#if USE_PERMLANE
#define PVSTEP(RA0, RA1, RB0, RB1, VF0, VF1, O0, O1) {                 \
    unsigned x0 = RA0, y0 = RB0, x1 = RA1, y1 = RB1;                   \
    u32x2 r_;                                                          \
    r_ = __builtin_amdgcn_permlane32_swap(x0, y0, false, false); x0 = r_.x; y0 = r_.y; \
    r_ = __builtin_amdgcn_permlane16_swap(x0, y0, false, false); x0 = r_.x; y0 = r_.y; \
    r_ = __builtin_amdgcn_permlane32_swap(x1, y1, false, false); x1 = r_.x; y1 = r_.y; \
    r_ = __builtin_amdgcn_permlane16_swap(x1, y1, false, false); x1 = r_.x; y1 = r_.y; \
    union { u32x4 u; bf16x8 b; } pf_; pf_.u = u32x4{x0, x1, y0, y1};   \
    __builtin_amdgcn_s_setprio(1);                                     \
    O0 = __builtin_amdgcn_mfma_f32_16x16x32_bf16(VF0, pf_.b, O0, 0, 0, 0); \
    O1 = __builtin_amdgcn_mfma_f32_16x16x32_bf16(VF1, pf_.b, O1, 0, 0, 0); \
    __builtin_amdgcn_s_setprio(0);                                     \
}
#else
#define PVSTEP(RA0, RA1, RB0, RB1, VF0, VF1, O0, O1) {                 \
    union { u32x2 u; sh4 s; } wa_, wb_;                                \
    wa_.u = u32x2{RA0, RA1}; wb_.u = u32x2{RB0, RB1};                  \
    *reinterpret_cast<sh4*>(&PT[w][l16][quad * 4])      = wa_.s;       \
    *reinterpret_cast<sh4*>(&PT[w][l16][16 + quad * 4]) = wb_.s;       \
    bf16x8 pf_ = *reinterpret_cast<bf16x8*>(&PT[w][l16][quad * 8]);    \
    O0 = __builtin_amdgcn_mfma_f32_16x16x32_bf16(VF0, pf_, O0, 0, 0, 0); \
    O1 = __builtin_amdgcn_mfma_f32_16x16x32_bf16(VF1, pf_, O1, 0, 0, 0); \
}
#endif

#define PROCJ(f, QF, LACC, O0, O1) {                                     \
    __builtin_amdgcn_s_setprio(1);                                       \
    f32x4 s0 = __builtin_amdgcn_mfma_f32_16x16x32_bf16(f.k0, QF, zero, 0, 0, 0); \
    f32x4 s1 = __builtin_amdgcn_mfma_f32_16x16x32_bf16(f.k1, QF, zero, 0, 0, 0); \
    f32x4 s2 = __builtin_amdgcn_mfma_f32_16x16x32_bf16(f.k2, QF, zero, 0, 0, 0); \
    f32x4 s3 = __builtin_amdgcn_mfma_f32_16x16x32_bf16(f.k3, QF, zero, 0, 0, 0); \
    __builtin_amdgcn_s_setprio(0);                                       \
    unsigned R00, R01, R10, R11, R20, R21, R30, R31;                     \
    EXPPACK(s0, R00, R01, LACC); EXPPACK(s1, R10, R11, LACC);            \
    EXPPACK(s2, R20, R21, LACC); EXPPACK(s3, R30, R31, LACC);            \
    PVSTEP(R00, R01, R10, R11, f.v00, f.v01, O0, O1);                    \
    PVSTEP(R20, R21, R30, R31, f.v10, f.v11, O0, O1);                    \
}

#define PROCALL(f) {                                                     \
    PROCJ(f, qf0, la0, o00, o01);                                        \
    PROCJ(f, qf1, la1, o10, o11);                                        \
    PROCJ(f, qf2, la2, o20, o21);                                        \
    PROCJ(f, qf3, la3, o30, o31);                                        \
}

__global__ __launch_bounds__(256, 2) void attn_kernel(
    const short* __restrict__ Qs, const short* __restrict__ Ks,
    const short* __restrict__ Vt, short* __restrict__ Ot) {
    __shared__ float OL[4][64][36];   // [split][q][d] partial O
    __shared__ float Ll[4][64];       // [split][q] partial rowsum
#if !USE_PERMLANE
    __shared__ short PT[4][16][36];
#endif

    int bh = blockIdx.x;
    int q0 = blockIdx.y * 64;
    int t = threadIdx.x, lane = t & 63, w = t >> 6;   // w = key-split 0..3
    int l16 = lane & 15, quad = lane >> 4;

    const short* Qbase = Qs + ((size_t)bh * N_N + q0 + l16) * DK_N + quad * 8;
    bf16x8 qf0 = *reinterpret_cast<const bf16x8*>(Qbase + 0 * 16 * DK_N);
    bf16x8 qf1 = *reinterpret_cast<const bf16x8*>(Qbase + 1 * 16 * DK_N);
    bf16x8 qf2 = *reinterpret_cast<const bf16x8*>(Qbase + 2 * 16 * DK_N);
    bf16x8 qf3 = *reinterpret_cast<const bf16x8*>(Qbase + 3 * 16 * DK_N);
    const short* Kp  = Ks + ((size_t)bh * KN_N + l16) * DK_N + quad * 8;
    const short* Vp0 = Vt + ((size_t)bh * DK_N + l16) * KN_N + quad * 8;

    const f32x4 zero = {0.f, 0.f, 0.f, 0.f};
    f32x4 o00 = zero, o01 = zero, o10 = zero, o11 = zero;
    f32x4 o20 = zero, o21 = zero, o30 = zero, o31 = zero;
    float la0 = 0.f, la1 = 0.f, la2 = 0.f, la3 = 0.f;
    int kbase = w * 768;              // this wave's 768-key slice, 12 tiles

    Frags cur = ldfr(Kp, Vp0, kbase);
#pragma unroll 2
    for (int i = 0; i < 11; ++i) {
        Frags nxt = ldfr(Kp, Vp0, kbase + (i + 1) * 64);   // prefetch next tile
        PROCALL(cur);
        cur = nxt;
    }
    PROCALL(cur);

    la0 += __shfl_xor(la0, 16); la0 += __shfl_xor(la0, 32);
    la1 += __shfl_xor(la1, 16); la1 += __shfl_xor(la1, 32);
    la2 += __shfl_xor(la2, 16); la2 += __shfl_xor(la2, 32);
    la3 += __shfl_xor(la3, 16); la3 += __shfl_xor(la3, 32);

    *reinterpret_cast<fl4*>(&OL[w][ 0 + l16][quad * 4])      = o00;
    *reinterpret_cast<fl4*>(&OL[w][ 0 + l16][16 + quad * 4]) = o01;
    *reinterpret_cast<fl4*>(&OL[w][16 + l16][quad * 4])      = o10;
    *reinterpret_cast<fl4*>(&OL[w][16 + l16][16 + quad * 4]) = o11;
    *reinterpret_cast<fl4*>(&OL[w][32 + l16][quad * 4])      = o20;
    *reinterpret_cast<fl4*>(&OL[w][32 + l16][16 + quad * 4]) = o21;
    *reinterpret_cast<fl4*>(&OL[w][48 + l16][quad * 4])      = o30;
    *reinterpret_cast<fl4*>(&OL[w][48 + l16][16 + quad * 4]) = o31;
    if (quad == 0) {
        Ll[w][ 0 + l16] = la0;
        Ll[w][16 + l16] = la1;
        Ll[w][32 + l16] = la2;
        Ll[w][48 + l16] = la3;
    }
    __syncthreads();

    int q = t >> 2, d0 = (t & 3) * 8;
    float rl = 1.0f / (Ll[0][q] + Ll[1][q] + Ll[2][q] + Ll[3][q]);
    fl4 a0 = *reinterpret_cast<fl4*>(&OL[0][q][d0]);
    fl4 a1 = *reinterpret_cast<fl4*>(&OL[0][q][d0 + 4]);
#pragma unroll
    for (int s = 1; s < 4; ++s) {
        fl4 b0 = *reinterpret_cast<fl4*>(&OL[s][q][d0]);
        fl4 b1 = *reinterpret_cast<fl4*>(&OL[s][q][d0 + 4]);
        a0.x += b0.x; a0.y += b0.y; a0.z += b0.z; a0.w += b0.w;
        a1.x += b1.x; a1.y += b1.y; a1.z += b1.z; a1.w += b1.w;
    }
    union { sh4 s[2]; bf16x8 v; } pk;
    pk.s[0].x = f2bf(a0.x * rl); pk.s[0].y = f2bf(a0.y * rl);
    pk.s[0].z = f2bf(a0.z * rl); pk.s[0].w = f2bf(a0.w * rl);
    pk.s[1].x = f2bf(a1.x * rl); pk.s[1].y = f2bf(a1.y * rl);
    pk.s[1].z = f2bf(a1.z * rl); pk.s[1].w = f2bf(a1.w * rl);
    int b = bh >> 3, h = bh & 7;
    *reinterpret_cast<bf16x8*>(
        Ot + ((size_t)b * N_N + q0 + q) * C_N + h * DK_N + d0) = pk.v;
}

// ---------------- kernel 4: output projection  grid(32 ct, 4 mt, 4 b) ------
// Epilogue repacks acc through LDS so stores are fl4 (16B) fully coalesced.
__global__ __launch_bounds__(256) void oproj_kernel(
    const short* __restrict__ Wo_bf, const float* __restrict__ bo,
    const short* __restrict__ Ot, float* __restrict__ out) {
    __shared__ float OS[64][36];      // 9.2 KB, padded (2-way max on write)
    int b = blockIdx.z, mt = blockIdx.y, ct = blockIdx.x;
    int t = threadIdx.x;
    int lane = t & 63, w = t >> 6;
    int l16 = lane & 15, quad = lane >> 4;
    int m0 = mt * 64, n0 = ct * 32;
    const short* Bsrc = Ot + ((size_t)b * N_N + n0) * C_N;
    int arow = m0 + w * 16 + l16;

    f32x4 acc[2];
    acc[0] = f32x4{0.f, 0.f, 0.f, 0.f};
    acc[1] = f32x4{0.f, 0.f, 0.f, 0.f};

#pragma unroll
    for (int kc = 0; kc < 256; kc += 32) {
        bf16x8 a = *reinterpret_cast<const bf16x8*>(Wo_bf + arow * C_N + kc + quad * 8);
#pragma unroll
        for (int nt = 0; nt < 2; ++nt) {
            bf16x8 bb = *reinterpret_cast<const bf16x8*>(Bsrc + (nt * 16 + l16) * C_N + kc + quad * 8);
            acc[nt] = __builtin_amdgcn_mfma_f32_16x16x32_bf16(a, bb, acc[nt], 0, 0, 0);
        }
    }

    // acc[nt][r]: row_l = w*16 + quad*4 + r, col = nt*16 + l16
#pragma unroll
    for (int r = 0; r < 4; ++r) {
        int row_l = w * 16 + quad * 4 + r;
        float bias = bo[m0 + row_l];
        OS[row_l][l16]      = acc[0][r] + bias;
        OS[row_l][16 + l16] = acc[1][r] + bias;
    }
    __syncthreads();

    // thread t -> (row = t>>2, 8 consecutive n), two fl4 stores
    int row_l = t >> 2, seg = t & 3;
    fl4 v0 = *reinterpret_cast<fl4*>(&OS[row_l][seg * 8]);
    fl4 v1 = *reinterpret_cast<fl4*>(&OS[row_l][seg * 8 + 4]);
    float* dst = out + ((size_t)b * C_N + m0 + row_l) * N_N + n0 + seg * 8;
    *reinterpret_cast<fl4*>(dst)     = v0;
    *reinterpret_cast<fl4*>(dst + 4) = v1;
}

// ---------------------------------------------------------------------------
extern "C" void kernel_launch(void* const* d_in, const int* in_sizes, int n_in,
                              void* d_out, int out_size, void* d_ws, size_t ws_size,
                              hipStream_t stream) {
    const float* x0 = (const float*)d_in[0];
    const float* x1 = (const float*)d_in[1];
    const float* x2 = (const float*)d_in[2];
    const float* g0 = (const float*)d_in[3];
    const float* g1 = (const float*)d_in[4];
    const float* g2 = (const float*)d_in[5];
    const float* Wq = (const float*)d_in[6];
    const float* bq = (const float*)d_in[7];
    const float* Wk = (const float*)d_in[8];
    const float* bk = (const float*)d_in[9];
    const float* Wv = (const float*)d_in[10];
    const float* bv = (const float*)d_in[11];
    const float* Wo = (const float*)d_in[12];
    const float* bo = (const float*)d_in[13];
    float* out = (float*)d_out;

    char* wsb = (char*)d_ws;
    short* Wbf = (short*)(wsb + 0);            //  512 KB (Wq|Wk|Wv|Wo bf16)
    short* Xt  = (short*)(wsb + 524288);       //  6 MB: [12][1024][256] swizzled
    short* Qs  = (short*)(wsb + 6815744);      //  2 MB: [4][8][1024][32]
    short* Ks  = (short*)(wsb + 8912896);      //  6 MB: [4][8][3072][32]
    short* Vt  = (short*)(wsb + 15204352);     //  6 MB: [4][8][32][3072]
    short* Ot  = (short*)(wsb + 21495808);     //  2 MB: [4][1024][256]

    prep_kernel<<<256, 256, 0, stream>>>(x0, x1, x2, g0, g1, g2,
                                         Wq, Wk, Wv, Wo, Xt, Wbf);
    qkv_kernel<<<dim3(48, 4, 4), 256, 0, stream>>>(Wbf, bq, bk, bv, Xt,
                                                   Qs, Ks, Vt);
    attn_kernel<<<dim3(32, 16), 256, 0, stream>>>(Qs, Ks, Vt, Ot);
    oproj_kernel<<<dim3(32, 4, 4), 256, 0, stream>>>(Wbf + 3 * 65536, bo, Ot, out);
}